// Round 3
// baseline (818.848 us; speedup 1.0000x reference)
//
#include <hip/hip_runtime.h>
#include <hip/hip_cooperative_groups.h>

namespace cg = cooperative_groups;

#define N_NODES 100000
#define N_EDGES 1250000
#define D 64
#define NBLK_N 391          // ceil(N_NODES/256)
#define COOP_BLOCKS 1024

// ---------------------------------------------------------------------------
// Workspace layout (bytes):
//   g      @ 0          : N*64 f32 = 25,600,000   (h @ W^T)
//   counts @ 25,600,000 : N i32    =    400,000
//   starts @ 26,000,000 : N i32    =    400,000
//   cursor @ 26,400,000 : N i32    =    400,000
//   bsums  @ 26,800,000 : 400 i32  =      1,600
//   packed @ 26,801,600 : E int2   = 10,000,000   ((src, e) sorted by dst)
// total = 36,801,600 B
// ---------------------------------------------------------------------------

// g = h @ W^T. Block = 256 threads handles 64 nodes; h-tile and W staged in
// LDS (rows padded to 17 float4 to break bank conflicts).
__global__ __launch_bounds__(256) void transform_kernel(const float* __restrict__ h,
                                                        const float* __restrict__ W,
                                                        float* __restrict__ g) {
    __shared__ float4 hs[64 * 17];
    __shared__ float4 ws4[64 * 17];
    int t = threadIdx.x;
    int n0 = blockIdx.x * 64;
#pragma unroll
    for (int k = 0; k < 4; ++k) {
        int f = t + k * 256;            // 0..1023 = 64 rows x 16 float4
        int r = f >> 4, c = f & 15;
        float4 hv = make_float4(0.f, 0.f, 0.f, 0.f);
        if (n0 + r < N_NODES) hv = ((const float4*)h)[(n0 + r) * 16 + c];
        hs[r * 17 + c] = hv;
        ws4[r * 17 + c] = ((const float4*)W)[f];
    }
    __syncthreads();

    int r = t >> 2;          // local node 0..63
    int oq = t & 3;          // output quarter
    float acc[16];
#pragma unroll
    for (int j = 0; j < 16; ++j) acc[j] = 0.f;

    for (int d4 = 0; d4 < 16; ++d4) {
        float4 hv = hs[r * 17 + d4];
#pragma unroll
        for (int j = 0; j < 16; ++j) {
            float4 wv = ws4[(oq * 16 + j) * 17 + d4];
            acc[j] += hv.x * wv.x + hv.y * wv.y + hv.z * wv.z + hv.w * wv.w;
        }
    }

    int n = n0 + r;
    if (n < N_NODES) {
        float4* gr = (float4*)(g + n * D + oq * 16);
        gr[0] = make_float4(acc[0], acc[1], acc[2], acc[3]);
        gr[1] = make_float4(acc[4], acc[5], acc[6], acc[7]);
        gr[2] = make_float4(acc[8], acc[9], acc[10], acc[11]);
        gr[3] = make_float4(acc[12], acc[13], acc[14], acc[15]);
    }
}

// ---------------------------------------------------------------------------
// Fused counting-sort pipeline: zero -> histogram -> scan -> scan-of-sums ->
// offsets -> permutation scatter (packed int2). One cooperative launch.
// ---------------------------------------------------------------------------
__global__ __launch_bounds__(256) void sort_pipeline_kernel(
    const int* __restrict__ src,
    const int* __restrict__ dst,
    const float* __restrict__ e,
    int* __restrict__ counts,
    int* __restrict__ starts,
    int* __restrict__ cursor,
    int* __restrict__ bsums,
    int2* __restrict__ packed) {
    cg::grid_group grid = cg::this_grid();
    __shared__ int tmp[256];
    __shared__ int carry;
    int t = threadIdx.x;
    int gid = blockIdx.x * 256 + t;
    int gsz = gridDim.x * 256;

    // phase 0: zero counts
    for (int i = gid; i < N_NODES; i += gsz) counts[i] = 0;
    grid.sync();

    // phase 1: histogram of dst
    for (int i = gid; i < N_EDGES; i += gsz) atomicAdd(&counts[dst[i]], 1);
    grid.sync();

    // phase 2: per-256-chunk exclusive scan; chunk totals -> bsums
    for (int c = blockIdx.x; c < NBLK_N; c += gridDim.x) {
        int i = c * 256 + t;
        int v = (i < N_NODES) ? counts[i] : 0;
        tmp[t] = v;
        __syncthreads();
#pragma unroll
        for (int off = 1; off < 256; off <<= 1) {
            int x = (t >= off) ? tmp[t - off] : 0;
            __syncthreads();
            tmp[t] += x;
            __syncthreads();
        }
        if (i < N_NODES) starts[i] = tmp[t] - v;
        if (t == 255) bsums[c] = tmp[255];
        __syncthreads();
    }
    grid.sync();

    // phase 3: block 0 exclusive-scans bsums[0..NBLK_N) (2 tiles + carry)
    if (blockIdx.x == 0) {
        if (t == 0) carry = 0;
        __syncthreads();
        for (int base = 0; base < NBLK_N; base += 256) {
            int i = base + t;
            int v = (i < NBLK_N) ? bsums[i] : 0;
            tmp[t] = v;
            __syncthreads();
#pragma unroll
            for (int off = 1; off < 256; off <<= 1) {
                int x = (t >= off) ? tmp[t - off] : 0;
                __syncthreads();
                tmp[t] += x;
                __syncthreads();
            }
            if (i < NBLK_N) bsums[i] = tmp[t] - v + carry;
            __syncthreads();
            if (t == 0) carry += tmp[255];
            __syncthreads();
        }
    }
    grid.sync();

    // phase 4: globalize starts; init cursor
    for (int i = gid; i < N_NODES; i += gsz) {
        int s = starts[i] + bsums[i >> 8];
        starts[i] = s;
        cursor[i] = s;
    }
    grid.sync();

    // phase 5: permutation scatter, single 8B packed store per edge
    for (int i = gid; i < N_EDGES; i += gsz) {
        int tt = dst[i];
        int pos = atomicAdd(&cursor[tt], 1);
        packed[pos] = make_int2(src[i], __float_as_int(e[i]));
    }
}

// ---------------------------------------------------------------------------
// One wave per node: lane d computes out[n,d] = b[d] + sum_k e_k * g[src_k,d].
// ---------------------------------------------------------------------------
__global__ __launch_bounds__(256) void gather_nodes_kernel(const float* __restrict__ g,
                                                           const int2* __restrict__ packed,
                                                           const int* __restrict__ starts,
                                                           const int* __restrict__ counts,
                                                           const float* __restrict__ b,
                                                           float* __restrict__ out) {
    int w = (blockIdx.x * 256 + threadIdx.x) >> 6;   // node id
    int lane = threadIdx.x & 63;
    if (w >= N_NODES) return;
    int start = starts[w];
    int end = start + counts[w];
    float acc = b[lane];
    int k = start;
    for (; k + 4 <= end; k += 4) {
        int2 p0 = packed[k];
        int2 p1 = packed[k + 1];
        int2 p2 = packed[k + 2];
        int2 p3 = packed[k + 3];
        acc += __int_as_float(p0.y) * g[p0.x * D + lane];
        acc += __int_as_float(p1.y) * g[p1.x * D + lane];
        acc += __int_as_float(p2.y) * g[p2.x * D + lane];
        acc += __int_as_float(p3.y) * g[p3.x * D + lane];
    }
    for (; k < end; ++k) {
        int2 p = packed[k];
        acc += __int_as_float(p.y) * g[p.x * D + lane];
    }
    out[w * D + lane] = acc;
}

// ---------------------------------------------------------------------------
extern "C" void kernel_launch(void* const* d_in, const int* in_sizes, int n_in,
                              void* d_out, int out_size, void* d_ws, size_t ws_size,
                              hipStream_t stream) {
    const float* h   = (const float*)d_in[0];
    const float* e   = (const float*)d_in[1];
    const int*   src = (const int*)d_in[2];
    const int*   dst = (const int*)d_in[3];
    const float* W   = (const float*)d_in[4];
    const float* b   = (const float*)d_in[5];
    float* out = (float*)d_out;

    char* ws = (char*)d_ws;
    float* g      = (float*)(ws);
    int*   counts = (int*)  (ws + 25600000);
    int*   starts = (int*)  (ws + 26000000);
    int*   cursor = (int*)  (ws + 26400000);
    int*   bsums  = (int*)  (ws + 26800000);
    int2*  packed = (int2*) (ws + 26801600);

    // 1) g = h @ W^T (independent of sort)
    transform_kernel<<<(N_NODES + 63) / 64, 256, 0, stream>>>(h, W, g);

    // 2) fused counting sort by dst (cooperative)
    {
        void* args[] = {(void*)&src, (void*)&dst, (void*)&e,
                        (void*)&counts, (void*)&starts, (void*)&cursor,
                        (void*)&bsums, (void*)&packed};
        hipLaunchCooperativeKernel((void*)sort_pipeline_kernel,
                                   dim3(COOP_BLOCKS), dim3(256), args, 0, stream);
    }

    // 3) pull-gather + bias
    gather_nodes_kernel<<<(N_NODES * 64 + 255) / 256, 256, 0, stream>>>(
        g, packed, starts, counts, b, out);
}

// Round 4
// 340.562 us; speedup vs baseline: 2.4044x; 2.4044x over previous
//
#include <hip/hip_runtime.h>

#define N_NODES 100000
#define N_EDGES 1250000
#define D 64
#define NBLK_N 391          // ceil(N_NODES/256)
#define NBLK_E 4883         // ceil(N_EDGES/256)

// ---------------------------------------------------------------------------
// Workspace layout (bytes):
//   g      @ 0          : N*64 f32 = 25,600,000   (h @ W^T)
//   counts @ 25,600,000 : N i32    =    400,000
//   starts @ 26,000,000 : N i32    =    400,000
//   cursor @ 26,400,000 : N i32    =    400,000
//   bsums  @ 26,800,000 : 400 i32  =      1,600
//   packed @ 26,801,600 : E int2   = 10,000,000   ((src, e) sorted by dst)
// total = 36,801,600 B
// ---------------------------------------------------------------------------

// g = h @ W^T. Block = 256 threads handles 64 nodes; h-tile and W staged in
// LDS (rows padded to 17 float4 to break bank conflicts).
__global__ __launch_bounds__(256) void transform_kernel(const float* __restrict__ h,
                                                        const float* __restrict__ W,
                                                        float* __restrict__ g) {
    __shared__ float4 hs[64 * 17];
    __shared__ float4 ws4[64 * 17];
    int t = threadIdx.x;
    int n0 = blockIdx.x * 64;
#pragma unroll
    for (int k = 0; k < 4; ++k) {
        int f = t + k * 256;            // 0..1023 = 64 rows x 16 float4
        int r = f >> 4, c = f & 15;
        float4 hv = make_float4(0.f, 0.f, 0.f, 0.f);
        if (n0 + r < N_NODES) hv = ((const float4*)h)[(n0 + r) * 16 + c];
        hs[r * 17 + c] = hv;
        ws4[r * 17 + c] = ((const float4*)W)[f];
    }
    __syncthreads();

    int r = t >> 2;          // local node 0..63
    int oq = t & 3;          // output quarter
    float acc[16];
#pragma unroll
    for (int j = 0; j < 16; ++j) acc[j] = 0.f;

    for (int d4 = 0; d4 < 16; ++d4) {
        float4 hv = hs[r * 17 + d4];
#pragma unroll
        for (int j = 0; j < 16; ++j) {
            float4 wv = ws4[(oq * 16 + j) * 17 + d4];
            acc[j] += hv.x * wv.x + hv.y * wv.y + hv.z * wv.z + hv.w * wv.w;
        }
    }

    int n = n0 + r;
    if (n < N_NODES) {
        float4* gr = (float4*)(g + n * D + oq * 16);
        gr[0] = make_float4(acc[0], acc[1], acc[2], acc[3]);
        gr[1] = make_float4(acc[4], acc[5], acc[6], acc[7]);
        gr[2] = make_float4(acc[8], acc[9], acc[10], acc[11]);
        gr[3] = make_float4(acc[12], acc[13], acc[14], acc[15]);
    }
}

__global__ __launch_bounds__(256) void histogram_kernel(const int* __restrict__ dst,
                                                        int* __restrict__ counts) {
    int i = blockIdx.x * 256 + threadIdx.x;
    if (i < N_EDGES) atomicAdd(&counts[dst[i]], 1);
}

// Per-block exclusive scan of counts -> starts (block-local), block totals -> bsums
__global__ __launch_bounds__(256) void block_scan_kernel(const int* __restrict__ counts,
                                                         int* __restrict__ starts,
                                                         int* __restrict__ bsums) {
    __shared__ int tmp[256];
    int t = threadIdx.x;
    int i = blockIdx.x * 256 + t;
    int v = (i < N_NODES) ? counts[i] : 0;
    tmp[t] = v;
    __syncthreads();
#pragma unroll
    for (int off = 1; off < 256; off <<= 1) {
        int x = (t >= off) ? tmp[t - off] : 0;
        __syncthreads();
        tmp[t] += x;
        __syncthreads();
    }
    if (i < N_NODES) starts[i] = tmp[t] - v;   // exclusive within block
    if (t == 255) bsums[blockIdx.x] = tmp[255];
}

// Single-block exclusive scan of the 391 block sums (512 >= NBLK_N)
__global__ __launch_bounds__(512) void sum_scan_kernel(int* __restrict__ bsums) {
    __shared__ int tmp[512];
    int t = threadIdx.x;
    int v = (t < NBLK_N) ? bsums[t] : 0;
    tmp[t] = v;
    __syncthreads();
#pragma unroll
    for (int off = 1; off < 512; off <<= 1) {
        int x = (t >= off) ? tmp[t - off] : 0;
        __syncthreads();
        tmp[t] += x;
        __syncthreads();
    }
    if (t < NBLK_N) bsums[t] = tmp[t] - v;     // exclusive
}

__global__ __launch_bounds__(256) void add_offsets_kernel(int* __restrict__ starts,
                                                          const int* __restrict__ bsums,
                                                          int* __restrict__ cursor) {
    int i = blockIdx.x * 256 + threadIdx.x;
    if (i < N_NODES) {
        int s = starts[i] + bsums[blockIdx.x];
        starts[i] = s;
        cursor[i] = s;
    }
}

// Permute edges into dst-sorted order; single 8B packed store per edge.
__global__ __launch_bounds__(256) void scatter_perm_kernel(const int* __restrict__ src,
                                                           const int* __restrict__ dst,
                                                           const float* __restrict__ e,
                                                           int* __restrict__ cursor,
                                                           int2* __restrict__ packed) {
    int i = blockIdx.x * 256 + threadIdx.x;
    if (i < N_EDGES) {
        int t = dst[i];
        int pos = atomicAdd(&cursor[t], 1);
        packed[pos] = make_int2(src[i], __float_as_int(e[i]));
    }
}

// One wave per node: lane d computes out[n,d] = b[d] + sum_k e_k * g[src_k,d].
__global__ __launch_bounds__(256) void gather_nodes_kernel(const float* __restrict__ g,
                                                           const int2* __restrict__ packed,
                                                           const int* __restrict__ starts,
                                                           const int* __restrict__ counts,
                                                           const float* __restrict__ b,
                                                           float* __restrict__ out) {
    int w = (blockIdx.x * 256 + threadIdx.x) >> 6;   // node id
    int lane = threadIdx.x & 63;
    if (w >= N_NODES) return;
    int start = starts[w];
    int end = start + counts[w];
    float acc = b[lane];
    int k = start;
    for (; k + 4 <= end; k += 4) {
        int2 p0 = packed[k];
        int2 p1 = packed[k + 1];
        int2 p2 = packed[k + 2];
        int2 p3 = packed[k + 3];
        acc += __int_as_float(p0.y) * g[p0.x * D + lane];
        acc += __int_as_float(p1.y) * g[p1.x * D + lane];
        acc += __int_as_float(p2.y) * g[p2.x * D + lane];
        acc += __int_as_float(p3.y) * g[p3.x * D + lane];
    }
    for (; k < end; ++k) {
        int2 p = packed[k];
        acc += __int_as_float(p.y) * g[p.x * D + lane];
    }
    out[w * D + lane] = acc;
}

// ---------------------------------------------------------------------------
extern "C" void kernel_launch(void* const* d_in, const int* in_sizes, int n_in,
                              void* d_out, int out_size, void* d_ws, size_t ws_size,
                              hipStream_t stream) {
    const float* h   = (const float*)d_in[0];
    const float* e   = (const float*)d_in[1];
    const int*   src = (const int*)d_in[2];
    const int*   dst = (const int*)d_in[3];
    const float* W   = (const float*)d_in[4];
    const float* b   = (const float*)d_in[5];
    float* out = (float*)d_out;

    char* ws = (char*)d_ws;
    float* g      = (float*)(ws);
    int*   counts = (int*)  (ws + 25600000);
    int*   starts = (int*)  (ws + 26000000);
    int*   cursor = (int*)  (ws + 26400000);
    int*   bsums  = (int*)  (ws + 26800000);
    int2*  packed = (int2*) (ws + 26801600);

    // 1) g = h @ W^T (independent of sort pipeline)
    transform_kernel<<<(N_NODES + 63) / 64, 256, 0, stream>>>(h, W, g);

    // 2) counting sort by dst (discrete kernels; coop fusion regressed in R3)
    hipMemsetAsync(counts, 0, N_NODES * sizeof(int), stream);
    histogram_kernel<<<NBLK_E, 256, 0, stream>>>(dst, counts);
    block_scan_kernel<<<NBLK_N, 256, 0, stream>>>(counts, starts, bsums);
    sum_scan_kernel<<<1, 512, 0, stream>>>(bsums);
    add_offsets_kernel<<<NBLK_N, 256, 0, stream>>>(starts, bsums, cursor);
    scatter_perm_kernel<<<NBLK_E, 256, 0, stream>>>(src, dst, e, cursor, packed);

    // 3) pull-gather + bias
    gather_nodes_kernel<<<(N_NODES * 64 + 255) / 256, 256, 0, stream>>>(
        g, packed, starts, counts, b, out);
}